// Round 1
// baseline (231.700 us; speedup 1.0000x reference)
//
#include <hip/hip_runtime.h>
#include <hip/hip_bf16.h>

typedef __attribute__((ext_vector_type(4))) float f32x4;
typedef __bf16 bf16x8v __attribute__((ext_vector_type(8)));

constexpr int NB = 2;
constexpr int NS = 2048;
constexpr int ND = 1024;
constexpr int NH = 16;
constexpr int NDK = 64;

// ---------------- projection GEMM (+ optional fused RoPE) ----------------
// C[m][n] = sum_d x[m][d] * w[n][d];  dst layout [B][H][S][64] bf16
__global__ void __launch_bounds__(256)
proj_kernel(const float* __restrict__ x, const float* __restrict__ w,
            const int* __restrict__ pos, __bf16* __restrict__ dst, int rope)
{
    constexpr int LD = 40;  // padded stride: 80B rows, 2-way banks (free), 16B aligned
    __shared__ __align__(16) __bf16 a_lds[64 * LD];
    __shared__ __align__(16) __bf16 b_lds[64 * LD];

    const int t = threadIdx.x;
    const int wid = t >> 6, lane = t & 63;
    const int g = lane >> 4, c = lane & 15;
    const int bm = blockIdx.x, bn = blockIdx.y;

    const int srow = t >> 2, scol = (t & 3) * 8;
    const float* ap = x + (size_t)(bm * 64 + srow) * ND + scol;
    const float* bp = w + (size_t)(bn * 64 + srow) * ND + scol;

    f32x4 acc[4] = {};

    for (int kt = 0; kt < ND / 32; ++kt) {
        const f32x4 a0 = *(const f32x4*)(ap + kt * 32);
        const f32x4 a1 = *(const f32x4*)(ap + kt * 32 + 4);
        const f32x4 b0 = *(const f32x4*)(bp + kt * 32);
        const f32x4 b1 = *(const f32x4*)(bp + kt * 32 + 4);
        __syncthreads();  // previous iteration's LDS reads done
        bf16x8v av, bv;
#pragma unroll
        for (int j = 0; j < 4; ++j) {
            av[j] = (__bf16)a0[j]; av[4 + j] = (__bf16)a1[j];
            bv[j] = (__bf16)b0[j]; bv[4 + j] = (__bf16)b1[j];
        }
        *(bf16x8v*)&a_lds[srow * LD + scol] = av;
        *(bf16x8v*)&b_lds[srow * LD + scol] = bv;
        __syncthreads();
        const bf16x8v af = *(const bf16x8v*)&a_lds[(wid * 16 + c) * LD + g * 8];
#pragma unroll
        for (int f = 0; f < 4; ++f) {
            const bf16x8v bf_ = *(const bf16x8v*)&b_lds[(f * 16 + c) * LD + g * 8];
            acc[f] = __builtin_amdgcn_mfma_f32_16x16x32_bf16(af, bf_, acc[f], 0, 0, 0);
        }
    }

    // epilogue: C/D layout col=lane&15, row=(lane>>4)*4+i  [m89]
    const int m0 = bm * 64 + wid * 16 + g * 4;
#pragma unroll
    for (int f = 0; f < 4; ++f) {
        const int d = f * 16 + c;  // head-dim index (bn = head, since BN==64==D_K)
        float vals[4] = {acc[f][0], acc[f][1], acc[f][2], acc[f][3]};
        if (rope) {
            // pair (2t,2t+1) lives in lanes l / l^1 (same freq)
            const float freq = __expf((float)(d & ~1) * (-9.210340371976184f / 64.0f));
#pragma unroll
            for (int i = 0; i < 4; ++i) {
                const int m = m0 + i;
                const float angle = (float)pos[m & (NS - 1)] * freq;
                float sn, cs;
                sincosf(angle, &sn, &cs);
                const float mine = vals[i];
                const float oth = __shfl_xor(mine, 1, 64);
                vals[i] = (d & 1) ? (oth * sn + mine * cs) : (mine * cs - oth * sn);
            }
        }
#pragma unroll
        for (int i = 0; i < 4; ++i) {
            const int m = m0 + i;
            dst[(((size_t)(m >> 11) * NH + bn) * NS + (m & (NS - 1))) * NDK + d] =
                (__bf16)vals[i];
        }
    }
}

// ---------------- flash attention (causal, online softmax) ----------------
// q,k,v: [B*H][S][64] bf16.  o: [B*S][1024] bf16 (token-major for out-proj)
__global__ void __launch_bounds__(256)
attn_kernel(const __bf16* __restrict__ q, const __bf16* __restrict__ k,
            const __bf16* __restrict__ v, __bf16* __restrict__ o)
{
    __shared__ __align__(16) __bf16 k_lds[64 * 72];   // [k][d], stride 72 (144B)
    __shared__ __align__(16) __bf16 vt_lds[64 * 72];  // [d][k] transposed
    __shared__ __align__(16) __bf16 p_lds[4][16 * 72];

    const int t = threadIdx.x;
    const int wid = t >> 6, lane = t & 63;
    const int g = lane >> 4, c = lane & 15;
    const int qt = blockIdx.x, bh = blockIdx.y;
    const size_t base = (size_t)bh * NS * NDK;

    // Q fragments (A operand: row=lane&15, k=(lane>>4)*8+j), held in regs
    bf16x8v qf[2];
    {
        const __bf16* qp = q + base + (size_t)(qt * 64 + wid * 16 + c) * NDK + g * 8;
        qf[0] = *(const bf16x8v*)qp;
        qf[1] = *(const bf16x8v*)(qp + 32);
    }

    float mrun[4] = {-1e30f, -1e30f, -1e30f, -1e30f};
    float lrun[4] = {0.f, 0.f, 0.f, 0.f};
    f32x4 oacc[4] = {};

    for (int kt = 0; kt <= qt; ++kt) {
        __syncthreads();
        // stage K tile (row-major, coalesced 16B)
#pragma unroll
        for (int p = 0; p < 2; ++p) {
            const int cid = t + p * 256;
            const int row = cid >> 3, col = (cid & 7) * 8;
            *(bf16x8v*)&k_lds[row * 72 + col] =
                *(const bf16x8v*)(k + base + (size_t)(kt * 64 + row) * NDK + col);
        }
        // stage V transposed: lane=d reads 8 k-rows (coalesced 2B/lane), one b128 write
#pragma unroll
        for (int p = 0; p < 2; ++p) {
            const int r0 = (wid * 2 + p) * 8;
            const __bf16* src = v + base + (size_t)(kt * 64 + r0) * NDK + lane;
            bf16x8v tmp;
#pragma unroll
            for (int j = 0; j < 8; ++j) tmp[j] = src[(size_t)j * NDK];
            *(bf16x8v*)&vt_lds[lane * 72 + r0] = tmp;
        }
        __syncthreads();

        // S = Q K^T
        f32x4 sf[4] = {};
#pragma unroll
        for (int f = 0; f < 4; ++f) {
            const bf16x8v k0 = *(const bf16x8v*)&k_lds[(f * 16 + c) * 72 + g * 8];
            const bf16x8v k1 = *(const bf16x8v*)&k_lds[(f * 16 + c) * 72 + 32 + g * 8];
            sf[f] = __builtin_amdgcn_mfma_f32_16x16x32_bf16(qf[0], k0, sf[f], 0, 0, 0);
            sf[f] = __builtin_amdgcn_mfma_f32_16x16x32_bf16(qf[1], k1, sf[f], 0, 0, 0);
        }

        // scale + causal mask (only diagonal tile)
        const bool diag = (kt == qt);
#pragma unroll
        for (int f = 0; f < 4; ++f)
#pragma unroll
            for (int i = 0; i < 4; ++i) {
                float sv = sf[f][i] * 0.125f;
                if (diag && (f * 16 + c) > (wid * 16 + g * 4 + i)) sv = -1e30f;
                sf[f][i] = sv;
            }

        // online softmax: row r=g*4+i lives in the 16-lane group sharing g
        float alpha[4];
#pragma unroll
        for (int i = 0; i < 4; ++i) {
            float r = fmaxf(fmaxf(sf[0][i], sf[1][i]), fmaxf(sf[2][i], sf[3][i]));
            r = fmaxf(r, __shfl_xor(r, 1, 64));
            r = fmaxf(r, __shfl_xor(r, 2, 64));
            r = fmaxf(r, __shfl_xor(r, 4, 64));
            r = fmaxf(r, __shfl_xor(r, 8, 64));
            const float mn = fmaxf(mrun[i], r);
            alpha[i] = __expf(mrun[i] - mn);
            mrun[i] = mn;
        }
#pragma unroll
        for (int f = 0; f < 4; ++f)
#pragma unroll
            for (int i = 0; i < 4; ++i)
                sf[f][i] = __expf(sf[f][i] - mrun[i]);
#pragma unroll
        for (int i = 0; i < 4; ++i) {
            float rs = sf[0][i] + sf[1][i] + sf[2][i] + sf[3][i];
            rs += __shfl_xor(rs, 1, 64);
            rs += __shfl_xor(rs, 2, 64);
            rs += __shfl_xor(rs, 4, 64);
            rs += __shfl_xor(rs, 8, 64);
            lrun[i] = lrun[i] * alpha[i] + rs;
        }
#pragma unroll
        for (int fd = 0; fd < 4; ++fd)
#pragma unroll
            for (int i = 0; i < 4; ++i) oacc[fd][i] *= alpha[i];

        // P -> LDS (D layout) then reload as A fragments (wave-private buffer)
#pragma unroll
        for (int f = 0; f < 4; ++f)
#pragma unroll
            for (int i = 0; i < 4; ++i)
                p_lds[wid][(g * 4 + i) * 72 + f * 16 + c] = (__bf16)sf[f][i];

        // O += P V  (B operand read from transposed V rows, contiguous)
#pragma unroll
        for (int ks = 0; ks < 2; ++ks) {
            const bf16x8v pf = *(const bf16x8v*)&p_lds[wid][c * 72 + ks * 32 + g * 8];
#pragma unroll
            for (int fd = 0; fd < 4; ++fd) {
                const bf16x8v vf =
                    *(const bf16x8v*)&vt_lds[(fd * 16 + c) * 72 + ks * 32 + g * 8];
                oacc[fd] = __builtin_amdgcn_mfma_f32_16x16x32_bf16(pf, vf, oacc[fd], 0, 0, 0);
            }
        }
    }

    const int b = bh >> 4, h = bh & 15;
#pragma unroll
    for (int fd = 0; fd < 4; ++fd)
#pragma unroll
        for (int i = 0; i < 4; ++i) {
            const int srow = qt * 64 + wid * 16 + g * 4 + i;
            o[((size_t)(b * NS + srow)) * ND + h * NDK + fd * 16 + c] =
                (__bf16)(oacc[fd][i] / lrun[i]);
        }
}

// ---------------- output projection: out[m][n] = sum_k a[m][k] wo[n][k] ----------------
__global__ void __launch_bounds__(256)
oproj_kernel(const __bf16* __restrict__ a, const float* __restrict__ w,
             float* __restrict__ out)
{
    constexpr int LD = 40;
    __shared__ __align__(16) __bf16 a_lds[64 * LD];
    __shared__ __align__(16) __bf16 b_lds[64 * LD];

    const int t = threadIdx.x;
    const int wid = t >> 6, lane = t & 63;
    const int g = lane >> 4, c = lane & 15;
    const int bm = blockIdx.x, bn = blockIdx.y;

    const int srow = t >> 2, scol = (t & 3) * 8;
    const __bf16* ap = a + (size_t)(bm * 64 + srow) * ND + scol;
    const float* bp = w + (size_t)(bn * 64 + srow) * ND + scol;

    f32x4 acc[4] = {};

    for (int kt = 0; kt < ND / 32; ++kt) {
        const bf16x8v av = *(const bf16x8v*)(ap + kt * 32);
        const f32x4 b0 = *(const f32x4*)(bp + kt * 32);
        const f32x4 b1 = *(const f32x4*)(bp + kt * 32 + 4);
        __syncthreads();
        bf16x8v bv;
#pragma unroll
        for (int j = 0; j < 4; ++j) { bv[j] = (__bf16)b0[j]; bv[4 + j] = (__bf16)b1[j]; }
        *(bf16x8v*)&a_lds[srow * LD + scol] = av;
        *(bf16x8v*)&b_lds[srow * LD + scol] = bv;
        __syncthreads();
        const bf16x8v af = *(const bf16x8v*)&a_lds[(wid * 16 + c) * LD + g * 8];
#pragma unroll
        for (int f = 0; f < 4; ++f) {
            const bf16x8v bf_ = *(const bf16x8v*)&b_lds[(f * 16 + c) * LD + g * 8];
            acc[f] = __builtin_amdgcn_mfma_f32_16x16x32_bf16(af, bf_, acc[f], 0, 0, 0);
        }
    }

    const int m0 = bm * 64 + wid * 16 + g * 4;
#pragma unroll
    for (int f = 0; f < 4; ++f) {
        const int n = bn * 64 + f * 16 + c;
#pragma unroll
        for (int i = 0; i < 4; ++i)
            out[(size_t)(m0 + i) * ND + n] = acc[f][i];
    }
}

extern "C" void kernel_launch(void* const* d_in, const int* in_sizes, int n_in,
                              void* d_out, int out_size, void* d_ws, size_t ws_size,
                              hipStream_t stream)
{
    const float* x  = (const float*)d_in[0];
    const float* wq = (const float*)d_in[1];
    const float* wk = (const float*)d_in[2];
    const float* wv = (const float*)d_in[3];
    const float* wo = (const float*)d_in[4];
    const int*   pos = (const int*)d_in[5];
    float* out = (float*)d_out;
    (void)in_sizes; (void)n_in; (void)out_size; (void)ws_size;

    const size_t per = (size_t)NB * NH * NS * NDK;  // 4M elems (8 MB bf16) each
    __bf16* qw = (__bf16*)d_ws;
    __bf16* kw = qw + per;
    __bf16* vw = kw + per;
    __bf16* aw = vw + per;  // attention output, token-major [B*S][1024]

    dim3 pg(NB * NS / 64, ND / 64);  // (64,16)
    proj_kernel<<<pg, 256, 0, stream>>>(x, wq, pos, qw, 1);
    proj_kernel<<<pg, 256, 0, stream>>>(x, wk, pos, kw, 1);
    proj_kernel<<<pg, 256, 0, stream>>>(x, wv, pos, vw, 0);

    dim3 ag(NS / 64, NB * NH);  // (32,32)
    attn_kernel<<<ag, 256, 0, stream>>>(qw, kw, vw, aw);

    oproj_kernel<<<pg, 256, 0, stream>>>(aw, wo, out);
}